// Round 9
// baseline (1158.447 us; speedup 1.0000x reference)
//
#include <hip/hip_runtime.h>
#include <hip/hip_bf16.h>
#include <math.h>

#define N_NODES 50000
#define N_EDGES 800000
#define NH 4
#define ND 64
#define NF 256   // NH*ND = feature width everywhere (IN=256 too)
#define NC 16
#define NEG_SLOPE 0.2f
#define NSLICE 8      // feature slices (32 feats = 64B each), slice = blockIdx&7 -> XCD-pinned
#define SLICE_W 32

typedef __attribute__((ext_vector_type(8))) short bf16x8;
typedef __attribute__((ext_vector_type(4))) float f32x4;

__device__ __forceinline__ float elu_f(float x) {
    return x > 0.f ? x : (__expf(x) - 1.f);
}

__device__ __forceinline__ ushort bf16_rne(float f) {
    union { float f; unsigned u; } v; v.f = f;
    unsigned u = v.u;
    u += 0x7fffu + ((u >> 16) & 1u);   // round-to-nearest-even
    return (ushort)(u >> 16);
}

__device__ __forceinline__ float bf2f(ushort u) {
    return __uint_as_float(((unsigned)u) << 16);
}

// ---------------- cast x (f32) -> bf16 ----------------
__global__ __launch_bounds__(256) void cast_bf16_kernel(const float* __restrict__ in,
                                                        ushort* __restrict__ out, int n8) {
    int i = blockIdx.x * 256 + threadIdx.x;
    if (i >= n8) return;
    float4 a = *(const float4*)(in + i * 8);
    float4 b = *(const float4*)(in + i * 8 + 4);
    ushort o[8] = {bf16_rne(a.x), bf16_rne(a.y), bf16_rne(a.z), bf16_rne(a.w),
                   bf16_rne(b.x), bf16_rne(b.y), bf16_rne(b.z), bf16_rne(b.w)};
    *(bf16x8*)(out + i * 8) = *(bf16x8*)o;
}

// ---- transpose+cast W[k][n] f32 -> Wt[n][k] bf16, two weights in one launch ----
__global__ __launch_bounds__(256) void castWt_kernel(const float* __restrict__ W0,
                                                     const float* __restrict__ W1,
                                                     ushort* __restrict__ Wt0,
                                                     ushort* __restrict__ Wt1) {
    const float* W = (blockIdx.x < 256) ? W0 : W1;
    ushort* Wt = (blockIdx.x < 256) ? Wt0 : Wt1;
    int n = blockIdx.x & 255;
    int k = threadIdx.x;
    Wt[n * 256 + k] = bf16_rne(W[k * 256 + n]);
}

// ---------------- GEMM: Cs (slice-major bf16) = A[M,256]bf16 @ Bt[n][k]bf16 ----------------
// 128x128 tile, BK=64, 256 threads (4 waves 2x2), 16x16x32 MFMA, XOR-swizzled LDS.
// Epilogue: slice-major store Cs[(col>>5)][row][col&31] + fused el/er dots.
__global__ __launch_bounds__(256) void gemm_bf16(const ushort* __restrict__ A,
                                                 const ushort* __restrict__ Bt,
                                                 ushort* __restrict__ Cs,
                                                 const float* __restrict__ al,
                                                 const float* __restrict__ ar,
                                                 float* __restrict__ el,
                                                 float* __restrict__ er, int M) {
    __shared__ __align__(16) ushort As[128 * 64];   // [row][k], 16B blocks XOR-swizzled
    __shared__ __align__(16) ushort Bs[128 * 64];   // [col][k], same
    const int t = threadIdx.x;
    const int l = t & 63;
    const int w = t >> 6;
    const int wm = (w >> 1) * 64, wn = (w & 1) * 64;
    const int m0 = blockIdx.x * 128, n0 = blockIdx.y * 128;
    const int lr = l & 15, lk = l >> 4;

    f32x4 acc[4][4] = {};
    const int sr = t >> 3;            // staging row-in-issue 0..31
    const int sc = t & 7;             // global 16B-block col
    const int scw = sc ^ (sr & 7);    // swizzled LDS block

    for (int k0 = 0; k0 < 256; k0 += 64) {
        #pragma unroll
        for (int q = 0; q < 4; ++q) {
            int row = q * 32 + sr;
            int ga = min(m0 + row, M - 1);
            bf16x8 va = *(const bf16x8*)(A + (size_t)ga * 256 + k0 + sc * 8);
            *(bf16x8*)(&As[row * 64 + scw * 8]) = va;
            bf16x8 vb = *(const bf16x8*)(Bt + (size_t)(n0 + row) * 256 + k0 + sc * 8);
            *(bf16x8*)(&Bs[row * 64 + scw * 8]) = vb;
        }
        __syncthreads();
        #pragma unroll
        for (int kk = 0; kk < 2; ++kk) {
            bf16x8 af[4], bfr[4];
            #pragma unroll
            for (int mi = 0; mi < 4; ++mi) {
                int row = wm + mi * 16 + lr;
                int kb = kk * 4 + lk;
                af[mi] = *(const bf16x8*)(&As[row * 64 + (kb ^ (row & 7)) * 8]);
            }
            #pragma unroll
            for (int ni = 0; ni < 4; ++ni) {
                int col = wn + ni * 16 + lr;
                int kb = kk * 4 + lk;
                bfr[ni] = *(const bf16x8*)(&Bs[col * 64 + (kb ^ (col & 7)) * 8]);
            }
            #pragma unroll
            for (int mi = 0; mi < 4; ++mi)
                #pragma unroll
                for (int ni = 0; ni < 4; ++ni)
                    acc[mi][ni] = __builtin_amdgcn_mfma_f32_16x16x32_bf16(af[mi], bfr[ni], acc[mi][ni], 0, 0, 0);
        }
        __syncthreads();
    }
    // this wave's head and its al/ar slice (d = ni*16 + lr)
    const int h = (n0 + wn) >> 6;
    float alv[4], arv[4];
    #pragma unroll
    for (int ni = 0; ni < 4; ++ni) {
        alv[ni] = al[h * ND + ni * 16 + lr];
        arv[ni] = ar[h * ND + ni * 16 + lr];
    }
    // C/D layout: col = lane&15, row = (lane>>4)*4 + reg  [m89-verified]
    #pragma unroll
    for (int mi = 0; mi < 4; ++mi) {
        #pragma unroll
        for (int j = 0; j < 4; ++j) {
            int row = m0 + wm + mi * 16 + lk * 4 + j;
            float pe = 0.f, pr = 0.f;
            #pragma unroll
            for (int ni = 0; ni < 4; ++ni) {
                int col = n0 + wn + ni * 16 + lr;
                float v = acc[mi][ni][j];
                pe += v * alv[ni];
                pr += v * arv[ni];
                if (row < M)
                    Cs[(size_t)(col >> 5) * N_NODES * SLICE_W + (size_t)row * SLICE_W + (col & 31)] = bf16_rne(v);
            }
            #pragma unroll
            for (int m = 1; m <= 8; m <<= 1) {
                pe += __shfl_xor(pe, m, 64);
                pr += __shfl_xor(pr, m, 64);
            }
            if (lr == 0 && row < M) {
                el[row * 4 + h] = pe;
                er[row * 4 + h] = pr;
            }
        }
    }
}

// -------- CSR build --------
__global__ __launch_bounds__(256) void hist_kernel(const int* __restrict__ dst, int* __restrict__ count) {
    int e = blockIdx.x * 256 + threadIdx.x;
    if (e < N_EDGES) atomicAdd(&count[dst[e]], 1);
}

__global__ __launch_bounds__(256) void scan1_kernel(const int* __restrict__ counts,
                                                    int* __restrict__ offs,
                                                    int* __restrict__ bsums) {
    __shared__ int sh[256];
    int tid = threadIdx.x;
    int i = blockIdx.x * 256 + tid;
    int v = (i < N_NODES) ? counts[i] : 0;
    sh[tid] = v;
    __syncthreads();
    #pragma unroll
    for (int ofs = 1; ofs < 256; ofs <<= 1) {
        int t = (tid >= ofs) ? sh[tid - ofs] : 0;
        __syncthreads();
        sh[tid] += t;
        __syncthreads();
    }
    if (i < N_NODES) offs[i] = sh[tid] - v;
    if (tid == 255) bsums[blockIdx.x] = sh[255];
}

__global__ __launch_bounds__(256) void scan2_kernel(const int* __restrict__ bsums,
                                                    int* __restrict__ boffs, int nb) {
    __shared__ int sh[256];
    int tid = threadIdx.x;
    int v = (tid < nb) ? bsums[tid] : 0;
    sh[tid] = v;
    __syncthreads();
    #pragma unroll
    for (int ofs = 1; ofs < 256; ofs <<= 1) {
        int t = (tid >= ofs) ? sh[tid - ofs] : 0;
        __syncthreads();
        sh[tid] += t;
        __syncthreads();
    }
    if (tid < nb) boffs[tid] = sh[tid] - v;
}

// scan3: finalize offs AND init cursor
__global__ __launch_bounds__(256) void scan3_kernel(int* __restrict__ offs,
                                                    const int* __restrict__ boffs,
                                                    int* __restrict__ cursor) {
    int i = blockIdx.x * 256 + threadIdx.x;
    if (i < N_NODES) {
        int v = offs[i] + boffs[i >> 8];
        offs[i] = v;
        cursor[i] = v;
    }
    if (i == 0) offs[N_NODES] = N_EDGES;
}

// scatter: store src AND dst node ids per slot
__global__ __launch_bounds__(256) void scatter_kernel(const int* __restrict__ src,
                                                      const int* __restrict__ dst,
                                                      int* __restrict__ cursor,
                                                      int* __restrict__ csrc,
                                                      int* __restrict__ cdst) {
    int e = blockIdx.x * 256 + threadIdx.x;
    if (e >= N_EDGES) return;
    int d = dst[e];
    int p = atomicAdd(&cursor[d], 1);
    csrc[p] = src[e];
    cdst[p] = d;
}

// -------- per-slot attention weights + denom accumulation --------
// w[i][h] = exp(leaky(el[src]+er[dst])); denom[dst][h] += w  (f32 atomics)
__global__ __launch_bounds__(256) void edge_w_kernel(const int* __restrict__ csrc,
                                                     const int* __restrict__ cdst,
                                                     const float* __restrict__ el,
                                                     const float* __restrict__ er,
                                                     float* __restrict__ w,
                                                     float* __restrict__ denom) {
    int i = blockIdx.x * 256 + threadIdx.x;
    if (i >= N_EDGES) return;
    int s = csrc[i], d = cdst[i];
    float4 lv = *(const float4*)(el + s * 4);
    float4 rv = *(const float4*)(er + d * 4);
    float lvv[4] = {lv.x, lv.y, lv.z, lv.w};
    float rvv[4] = {rv.x, rv.y, rv.z, rv.w};
    float o[4];
    #pragma unroll
    for (int hh = 0; hh < 4; ++hh) {
        float v = lvv[hh] + rvv[hh];
        v = v > 0.f ? v : NEG_SLOPE * v;
        o[hh] = __expf(v);
        atomicAdd(&denom[d * 4 + hh], o[hh]);
    }
    *(float4*)(w + (size_t)i * 4) = make_float4(o[0], o[1], o[2], o[3]);
}

// ======== sliced aggregation v2: 1 feat/lane, no cross-lane reduce ========
// wave = 2 nodes x 32 feats of one slice. slice = blockIdx&7 (XCD-pinned, 3.2MB/XCD).
// denom precomputed -> no dsum, no reduce. Uniform masked loop over max(degA,degB).
// All index math kept in 32-bit so loads use SGPR-base + voffset.
#define AGG2_BODY()                                                                \
    int b = blockIdx.x;                                                            \
    int slice = b & 7;                                                             \
    int wid = threadIdx.x >> 6;                                                    \
    int lane = threadIdx.x & 63;                                                   \
    int nn = lane >> 5;                                                            \
    int f = lane & 31;                                                             \
    int n = (b >> 3) * 8 + wid * 2 + nn;                                           \
    int h = slice >> 1;                                                            \
    const ushort* base = fs + (size_t)slice * (N_NODES * SLICE_W);                 \
    const float* wh = w + h;                                                       \
    int s0 = offs[n];                                                              \
    int deg = offs[n + 1] - s0;                                                    \
    int maxdeg = max(deg, __shfl_xor(deg, 32, 64));                                \
    int degc = max(deg - 1, 0);                                                    \
    float acc = 0.f;                                                               \
    _Pragma("unroll 2")                                                            \
    for (int t = 0; t < maxdeg; ++t) {                                             \
        int idx = s0 + min(t, degc);                                               \
        int sidv = csrc[idx];                                                      \
        float wv = t < deg ? wh[idx * 4] : 0.f;                                    \
        float fv = bf2f(base[sidv * SLICE_W + f]);                                 \
        acc += wv * fv;                                                            \
    }                                                                              \
    float inv = 1.f / fmaxf(denom[n * 4 + h], 1e-9f);                              \
    float v = elu_f(acc * inv);

// layer-0: write bf16 row-major hbuf (GEMM-1 A input)
__global__ __launch_bounds__(256) void agg2_l0(const ushort* __restrict__ fs,
                                               const int* __restrict__ csrc,
                                               const int* __restrict__ offs,
                                               const float* __restrict__ w,
                                               const float* __restrict__ denom,
                                               ushort* __restrict__ hbuf) {
    AGG2_BODY()
    hbuf[n * NF + slice * SLICE_W + f] = bf16_rne(v);
}

// final layer: write f32 heads into out[h][n][(slice&1)*32 + f]
__global__ __launch_bounds__(256) void agg2_final(const ushort* __restrict__ fs,
                                                  const int* __restrict__ csrc,
                                                  const int* __restrict__ offs,
                                                  const float* __restrict__ w,
                                                  const float* __restrict__ denom,
                                                  float* __restrict__ out) {
    AGG2_BODY()
    size_t p = (size_t)h * N_NODES * (ND + NC) + (size_t)n * (ND + NC)
             + (slice & 1) * SLICE_W + f;
    out[p] = v;
}

// -------- cluster softmax pass: reads heads from out, writes cs --------
__global__ __launch_bounds__(256) void cluster_kernel(const float* __restrict__ Wc,
                                                      const float* __restrict__ bc,
                                                      float* __restrict__ out) {
    int n = blockIdx.x * 4 + (threadIdx.x >> 6);
    int lane = threadIdx.x & 63;
    int h = lane >> 4;
    int g = lane & 15;
    size_t base = (size_t)h * N_NODES * (ND + NC) + (size_t)n * (ND + NC);
    float4 v = *(const float4*)(out + base + g * 4);
    float logit[NC];
    #pragma unroll
    for (int c = 0; c < NC; ++c) {
        int d0 = g * 4;
        float p = v.x * Wc[(d0 + 0) * NC + c] + v.y * Wc[(d0 + 1) * NC + c] +
                  v.z * Wc[(d0 + 2) * NC + c] + v.w * Wc[(d0 + 3) * NC + c];
        p += __shfl_xor(p, 1, 64);
        p += __shfl_xor(p, 2, 64);
        p += __shfl_xor(p, 4, 64);
        p += __shfl_xor(p, 8, 64);
        logit[c] = p + bc[c];
    }
    float m = logit[0];
    #pragma unroll
    for (int c = 1; c < NC; ++c) m = fmaxf(m, logit[c]);
    float ssum = 0.f;
    #pragma unroll
    for (int c = 0; c < NC; ++c) ssum += __expf(logit[c] - m);
    out[base + ND + g] = __expf(logit[g] - m) / ssum;
}

extern "C" void kernel_launch(void* const* d_in, const int* in_sizes, int n_in,
                              void* d_out, int out_size, void* d_ws, size_t ws_size,
                              hipStream_t stream) {
    const float* x   = (const float*)d_in[0];
    const int* src   = (const int*)d_in[1];
    const int* dst   = (const int*)d_in[2];
    const float* W0  = (const float*)d_in[3];
    const float* al0 = (const float*)d_in[4];
    const float* ar0 = (const float*)d_in[5];
    const float* W1  = (const float*)d_in[6];
    const float* al1 = (const float*)d_in[7];
    const float* ar1 = (const float*)d_in[8];
    const float* Wc  = (const float*)d_in[9];
    const float* bc  = (const float*)d_in[10];
    float* out = (float*)d_out;

    char* ws = (char*)d_ws;
    size_t off = 0;
    auto alloc = [&](size_t bytes) { void* p = ws + off; off = (off + bytes + 255) & ~(size_t)255; return p; };
    ushort* featsl = (ushort*)alloc((size_t)N_NODES * NF * 2);   // 25.6 MB slice-major GEMM out
    ushort* xbf    = (ushort*)alloc((size_t)N_NODES * NF * 2);   // 25.6 MB
    ushort* hbuf   = (ushort*)alloc((size_t)N_NODES * NF * 2);   // 25.6 MB layer0 out (row-major)
    ushort* Wt0    = (ushort*)alloc((size_t)256 * 256 * 2);
    ushort* Wt1    = (ushort*)alloc((size_t)256 * 256 * 2);
    float*  el     = (float*)alloc((size_t)N_NODES * NH * 4);
    float*  er     = (float*)alloc((size_t)N_NODES * NH * 4);
    float*  wbuf   = (float*)alloc((size_t)N_EDGES * NH * 4);    // 12.8 MB per-slot weights
    float*  denom  = (float*)alloc((size_t)N_NODES * NH * 4);    // 800 KB
    int* counts    = (int*)alloc((size_t)N_NODES * 4);
    int* offs      = (int*)alloc((size_t)(N_NODES + 1) * 4);
    int* cursor    = (int*)alloc((size_t)N_NODES * 4);
    int* csrc      = (int*)alloc((size_t)N_EDGES * 4);
    int* cdst      = (int*)alloc((size_t)N_EDGES * 4);
    int* bsums     = (int*)alloc(256 * 4);
    int* boffs     = (int*)alloc(256 * 4);

    const int EB = (N_EDGES + 255) / 256;          // 3125
    const int NB = (N_NODES + 255) / 256;          // 196
    const int GEMM_MB = (N_NODES + 127) / 128;     // 391
    const int C8 = (N_NODES * NF / 8 + 255) / 256;
    const int AGG_B = NSLICE * (N_NODES / 8);      // 8 * 6250 = 50000 blocks

    // ---- CSR build ----
    hipMemsetAsync(counts, 0, (size_t)N_NODES * 4, stream);
    hist_kernel<<<EB, 256, 0, stream>>>(dst, counts);
    scan1_kernel<<<NB, 256, 0, stream>>>(counts, offs, bsums);
    scan2_kernel<<<1, 256, 0, stream>>>(bsums, boffs, NB);
    scan3_kernel<<<NB, 256, 0, stream>>>(offs, boffs, cursor);
    scatter_kernel<<<EB, 256, 0, stream>>>(src, dst, cursor, csrc, cdst);

    // ---- weight + input casts ----
    castWt_kernel<<<512, 256, 0, stream>>>(W0, W1, Wt0, Wt1);
    cast_bf16_kernel<<<C8, 256, 0, stream>>>(x, xbf, N_NODES * NF / 8);

    // ---- Layer 0 ----
    gemm_bf16<<<dim3(GEMM_MB, 2), 256, 0, stream>>>(xbf, Wt0, featsl, al0, ar0, el, er, N_NODES);
    hipMemsetAsync(denom, 0, (size_t)N_NODES * NH * 4, stream);
    edge_w_kernel<<<EB, 256, 0, stream>>>(csrc, cdst, el, er, wbuf, denom);
    agg2_l0<<<AGG_B, 256, 0, stream>>>(featsl, csrc, offs, wbuf, denom, hbuf);

    // ---- Layer 1 ----
    gemm_bf16<<<dim3(GEMM_MB, 2), 256, 0, stream>>>(hbuf, Wt1, featsl, al1, ar1, el, er, N_NODES);
    hipMemsetAsync(denom, 0, (size_t)N_NODES * NH * 4, stream);
    edge_w_kernel<<<EB, 256, 0, stream>>>(csrc, cdst, el, er, wbuf, denom);
    agg2_final<<<AGG_B, 256, 0, stream>>>(featsl, csrc, offs, wbuf, denom, out);

    // ---- cluster softmax (needs full 64-wide heads) ----
    cluster_kernel<<<N_NODES / 4, 256, 0, stream>>>(Wc, bc, out);
}

// Round 10
// 816.720 us; speedup vs baseline: 1.4184x; 1.4184x over previous
//
#include <hip/hip_runtime.h>
#include <hip/hip_bf16.h>
#include <math.h>

#define N_NODES 50000
#define N_EDGES 800000
#define NH 4
#define ND 64
#define NF 256   // NH*ND = feature width everywhere (IN=256 too)
#define NC 16
#define NEG_SLOPE 0.2f
#define NSLICE 8      // feature slices (32 feats = 64B each), slice = blockIdx&7 -> XCD-pinned
#define SLICE_W 32

typedef __attribute__((ext_vector_type(8))) short bf16x8;
typedef __attribute__((ext_vector_type(4))) float f32x4;

__device__ __forceinline__ float elu_f(float x) {
    return x > 0.f ? x : (__expf(x) - 1.f);
}

__device__ __forceinline__ ushort bf16_rne(float f) {
    union { float f; unsigned u; } v; v.f = f;
    unsigned u = v.u;
    u += 0x7fffu + ((u >> 16) & 1u);   // round-to-nearest-even
    return (ushort)(u >> 16);
}

__device__ __forceinline__ float bf2f(ushort u) {
    return __uint_as_float(((unsigned)u) << 16);
}

// ---------------- cast x (f32) -> bf16 ----------------
__global__ __launch_bounds__(256) void cast_bf16_kernel(const float* __restrict__ in,
                                                        ushort* __restrict__ out, int n8) {
    int i = blockIdx.x * 256 + threadIdx.x;
    if (i >= n8) return;
    float4 a = *(const float4*)(in + i * 8);
    float4 b = *(const float4*)(in + i * 8 + 4);
    ushort o[8] = {bf16_rne(a.x), bf16_rne(a.y), bf16_rne(a.z), bf16_rne(a.w),
                   bf16_rne(b.x), bf16_rne(b.y), bf16_rne(b.z), bf16_rne(b.w)};
    *(bf16x8*)(out + i * 8) = *(bf16x8*)o;
}

// ---- transpose+cast W[k][n] f32 -> Wt[n][k] bf16, two weights in one launch ----
__global__ __launch_bounds__(256) void castWt_kernel(const float* __restrict__ W0,
                                                     const float* __restrict__ W1,
                                                     ushort* __restrict__ Wt0,
                                                     ushort* __restrict__ Wt1) {
    const float* W = (blockIdx.x < 256) ? W0 : W1;
    ushort* Wt = (blockIdx.x < 256) ? Wt0 : Wt1;
    int n = blockIdx.x & 255;
    int k = threadIdx.x;
    Wt[n * 256 + k] = bf16_rne(W[k * 256 + n]);
}

// ---------------- GEMM: Cs (slice-major bf16) = A[M,256]bf16 @ Bt[n][k]bf16 ----------------
// 128x128 tile, BK=64, 256 threads (4 waves 2x2), 16x16x32 MFMA, XOR-swizzled LDS.
// Epilogue: slice-major store Cs[(col>>5)][row][col&31] + fused el/er dots.
__global__ __launch_bounds__(256) void gemm_bf16(const ushort* __restrict__ A,
                                                 const ushort* __restrict__ Bt,
                                                 ushort* __restrict__ Cs,
                                                 const float* __restrict__ al,
                                                 const float* __restrict__ ar,
                                                 float* __restrict__ el,
                                                 float* __restrict__ er, int M) {
    __shared__ __align__(16) ushort As[128 * 64];   // [row][k], 16B blocks XOR-swizzled
    __shared__ __align__(16) ushort Bs[128 * 64];   // [col][k], same
    const int t = threadIdx.x;
    const int l = t & 63;
    const int w = t >> 6;
    const int wm = (w >> 1) * 64, wn = (w & 1) * 64;
    const int m0 = blockIdx.x * 128, n0 = blockIdx.y * 128;
    const int lr = l & 15, lk = l >> 4;

    f32x4 acc[4][4] = {};
    const int sr = t >> 3;            // staging row-in-issue 0..31
    const int sc = t & 7;             // global 16B-block col
    const int scw = sc ^ (sr & 7);    // swizzled LDS block

    for (int k0 = 0; k0 < 256; k0 += 64) {
        #pragma unroll
        for (int q = 0; q < 4; ++q) {
            int row = q * 32 + sr;
            int ga = min(m0 + row, M - 1);
            bf16x8 va = *(const bf16x8*)(A + (size_t)ga * 256 + k0 + sc * 8);
            *(bf16x8*)(&As[row * 64 + scw * 8]) = va;
            bf16x8 vb = *(const bf16x8*)(Bt + (size_t)(n0 + row) * 256 + k0 + sc * 8);
            *(bf16x8*)(&Bs[row * 64 + scw * 8]) = vb;
        }
        __syncthreads();
        #pragma unroll
        for (int kk = 0; kk < 2; ++kk) {
            bf16x8 af[4], bfr[4];
            #pragma unroll
            for (int mi = 0; mi < 4; ++mi) {
                int row = wm + mi * 16 + lr;
                int kb = kk * 4 + lk;
                af[mi] = *(const bf16x8*)(&As[row * 64 + (kb ^ (row & 7)) * 8]);
            }
            #pragma unroll
            for (int ni = 0; ni < 4; ++ni) {
                int col = wn + ni * 16 + lr;
                int kb = kk * 4 + lk;
                bfr[ni] = *(const bf16x8*)(&Bs[col * 64 + (kb ^ (col & 7)) * 8]);
            }
            #pragma unroll
            for (int mi = 0; mi < 4; ++mi)
                #pragma unroll
                for (int ni = 0; ni < 4; ++ni)
                    acc[mi][ni] = __builtin_amdgcn_mfma_f32_16x16x32_bf16(af[mi], bfr[ni], acc[mi][ni], 0, 0, 0);
        }
        __syncthreads();
    }
    // this wave's head and its al/ar slice (d = ni*16 + lr)
    const int h = (n0 + wn) >> 6;
    float alv[4], arv[4];
    #pragma unroll
    for (int ni = 0; ni < 4; ++ni) {
        alv[ni] = al[h * ND + ni * 16 + lr];
        arv[ni] = ar[h * ND + ni * 16 + lr];
    }
    // C/D layout: col = lane&15, row = (lane>>4)*4 + reg  [m89-verified]
    #pragma unroll
    for (int mi = 0; mi < 4; ++mi) {
        #pragma unroll
        for (int j = 0; j < 4; ++j) {
            int row = m0 + wm + mi * 16 + lk * 4 + j;
            float pe = 0.f, pr = 0.f;
            #pragma unroll
            for (int ni = 0; ni < 4; ++ni) {
                int col = n0 + wn + ni * 16 + lr;
                float v = acc[mi][ni][j];
                pe += v * alv[ni];
                pr += v * arv[ni];
                if (row < M)
                    Cs[(size_t)(col >> 5) * N_NODES * SLICE_W + (size_t)row * SLICE_W + (col & 31)] = bf16_rne(v);
            }
            #pragma unroll
            for (int m = 1; m <= 8; m <<= 1) {
                pe += __shfl_xor(pe, m, 64);
                pr += __shfl_xor(pr, m, 64);
            }
            if (lr == 0 && row < M) {
                el[row * 4 + h] = pe;
                er[row * 4 + h] = pr;
            }
        }
    }
}

// -------- CSR build --------
__global__ __launch_bounds__(256) void hist_kernel(const int* __restrict__ dst, int* __restrict__ count) {
    int e = blockIdx.x * 256 + threadIdx.x;
    if (e < N_EDGES) atomicAdd(&count[dst[e]], 1);
}

__global__ __launch_bounds__(256) void scan1_kernel(const int* __restrict__ counts,
                                                    int* __restrict__ offs,
                                                    int* __restrict__ bsums) {
    __shared__ int sh[256];
    int tid = threadIdx.x;
    int i = blockIdx.x * 256 + tid;
    int v = (i < N_NODES) ? counts[i] : 0;
    sh[tid] = v;
    __syncthreads();
    #pragma unroll
    for (int ofs = 1; ofs < 256; ofs <<= 1) {
        int t = (tid >= ofs) ? sh[tid - ofs] : 0;
        __syncthreads();
        sh[tid] += t;
        __syncthreads();
    }
    if (i < N_NODES) offs[i] = sh[tid] - v;
    if (tid == 255) bsums[blockIdx.x] = sh[255];
}

__global__ __launch_bounds__(256) void scan2_kernel(const int* __restrict__ bsums,
                                                    int* __restrict__ boffs, int nb) {
    __shared__ int sh[256];
    int tid = threadIdx.x;
    int v = (tid < nb) ? bsums[tid] : 0;
    sh[tid] = v;
    __syncthreads();
    #pragma unroll
    for (int ofs = 1; ofs < 256; ofs <<= 1) {
        int t = (tid >= ofs) ? sh[tid - ofs] : 0;
        __syncthreads();
        sh[tid] += t;
        __syncthreads();
    }
    if (tid < nb) boffs[tid] = sh[tid] - v;
}

// scan3: finalize offs AND init cursor
__global__ __launch_bounds__(256) void scan3_kernel(int* __restrict__ offs,
                                                    const int* __restrict__ boffs,
                                                    int* __restrict__ cursor) {
    int i = blockIdx.x * 256 + threadIdx.x;
    if (i < N_NODES) {
        int v = offs[i] + boffs[i >> 8];
        offs[i] = v;
        cursor[i] = v;
    }
    if (i == 0) offs[N_NODES] = N_EDGES;
}

// scatter: store src AND dst node ids per slot
__global__ __launch_bounds__(256) void scatter_kernel(const int* __restrict__ src,
                                                      const int* __restrict__ dst,
                                                      int* __restrict__ cursor,
                                                      int* __restrict__ csrc,
                                                      int* __restrict__ cdst) {
    int e = blockIdx.x * 256 + threadIdx.x;
    if (e >= N_EDGES) return;
    int d = dst[e];
    int p = atomicAdd(&cursor[d], 1);
    csrc[p] = src[e];
    cdst[p] = d;
}

// -------- per-slot attention weights + denom accumulation --------
// head-major planes: w[h][i] = exp(leaky(el[src]+er[dst])); denom[h][dst] += w
__global__ __launch_bounds__(256) void edge_w_kernel(const int* __restrict__ csrc,
                                                     const int* __restrict__ cdst,
                                                     const float* __restrict__ el,
                                                     const float* __restrict__ er,
                                                     float* __restrict__ w,
                                                     float* __restrict__ denom) {
    int i = blockIdx.x * 256 + threadIdx.x;
    if (i >= N_EDGES) return;
    int s = csrc[i], d = cdst[i];
    float4 lv = *(const float4*)(el + s * 4);
    float4 rv = *(const float4*)(er + d * 4);
    float lvv[4] = {lv.x, lv.y, lv.z, lv.w};
    float rvv[4] = {rv.x, rv.y, rv.z, rv.w};
    #pragma unroll
    for (int hh = 0; hh < 4; ++hh) {
        float v = lvv[hh] + rvv[hh];
        v = v > 0.f ? v : NEG_SLOPE * v;
        float o = __expf(v);
        w[(size_t)hh * N_EDGES + i] = o;
        atomicAdd(&denom[hh * N_NODES + d], o);
    }
}

// ======== sliced aggregation v3: wave = 8 nodes x 1 slice ========
// lane = (nn 0..7, fc 0..7): 8-lane group owns node nn's 64B slice row.
// 8 independent per-node edge chains per wave (MLP by construction);
// acc = float4/lane, denom precomputed -> NO cross-lane reduce at all.
// slice = blockIdx&7 -> XCD-pinned 3.2MB working set [r8-proven].
#define AGG3_BODY()                                                                \
    int b = blockIdx.x;                                                            \
    int slice = b & 7;                                                             \
    int wid = threadIdx.x >> 6;                                                    \
    int lane = threadIdx.x & 63;                                                   \
    int nn = lane >> 3;                                                            \
    int fc = lane & 7;                                                             \
    int h = slice >> 1;                                                            \
    int n = (b >> 3) * 32 + wid * 8 + nn;                                          \
    int nc = min(n, N_NODES - 1);                                                  \
    const ushort* base = fs + (size_t)slice * (N_NODES * SLICE_W);                 \
    const float* wh = w + (size_t)h * N_EDGES;                                     \
    int s0 = offs[nc];                                                             \
    int deg = (n < N_NODES) ? (offs[nc + 1] - s0) : 0;                             \
    int degc = max(deg - 1, 0);                                                    \
    int md = deg;                                                                  \
    md = max(md, __shfl_xor(md, 8, 64));                                           \
    md = max(md, __shfl_xor(md, 16, 64));                                          \
    md = max(md, __shfl_xor(md, 32, 64));                                          \
    float4 acc = make_float4(0.f, 0.f, 0.f, 0.f);                                  \
    _Pragma("unroll 2")                                                            \
    for (int t = 0; t < md; ++t) {                                                 \
        int idx = s0 + min(t, degc);                                               \
        int sid = csrc[idx];                                                       \
        float wv = t < deg ? wh[idx] : 0.f;                                        \
        ushort4 fr = *(const ushort4*)(base + sid * SLICE_W + fc * 4);             \
        acc.x += wv * bf2f(fr.x);                                                  \
        acc.y += wv * bf2f(fr.y);                                                  \
        acc.z += wv * bf2f(fr.z);                                                  \
        acc.w += wv * bf2f(fr.w);                                                  \
    }                                                                              \
    float inv = 1.f / fmaxf(denom[h * N_NODES + nc], 1e-9f);

// layer-0: write bf16 row-major hbuf (GEMM-1 A input)
__global__ __launch_bounds__(256) void agg3_l0(const ushort* __restrict__ fs,
                                               const int* __restrict__ csrc,
                                               const int* __restrict__ offs,
                                               const float* __restrict__ w,
                                               const float* __restrict__ denom,
                                               ushort* __restrict__ hbuf) {
    AGG3_BODY()
    if (n < N_NODES) {
        ushort o[4] = {bf16_rne(elu_f(acc.x * inv)), bf16_rne(elu_f(acc.y * inv)),
                       bf16_rne(elu_f(acc.z * inv)), bf16_rne(elu_f(acc.w * inv))};
        *(ushort4*)(hbuf + (size_t)n * NF + slice * SLICE_W + fc * 4) = *(ushort4*)o;
    }
}

// final layer: write f32 heads into out[h][n][(slice&1)*32 + fc*4 ..]
__global__ __launch_bounds__(256) void agg3_final(const ushort* __restrict__ fs,
                                                  const int* __restrict__ csrc,
                                                  const int* __restrict__ offs,
                                                  const float* __restrict__ w,
                                                  const float* __restrict__ denom,
                                                  float* __restrict__ out) {
    AGG3_BODY()
    if (n < N_NODES) {
        float4 v = make_float4(elu_f(acc.x * inv), elu_f(acc.y * inv),
                               elu_f(acc.z * inv), elu_f(acc.w * inv));
        size_t p = (size_t)h * N_NODES * (ND + NC) + (size_t)n * (ND + NC)
                 + (slice & 1) * SLICE_W + fc * 4;
        *(float4*)(out + p) = v;
    }
}

// -------- cluster softmax pass: reads heads from out, writes cs --------
__global__ __launch_bounds__(256) void cluster_kernel(const float* __restrict__ Wc,
                                                      const float* __restrict__ bc,
                                                      float* __restrict__ out) {
    int n = blockIdx.x * 4 + (threadIdx.x >> 6);
    int lane = threadIdx.x & 63;
    int h = lane >> 4;
    int g = lane & 15;
    size_t base = (size_t)h * N_NODES * (ND + NC) + (size_t)n * (ND + NC);
    float4 v = *(const float4*)(out + base + g * 4);
    float logit[NC];
    #pragma unroll
    for (int c = 0; c < NC; ++c) {
        int d0 = g * 4;
        float p = v.x * Wc[(d0 + 0) * NC + c] + v.y * Wc[(d0 + 1) * NC + c] +
                  v.z * Wc[(d0 + 2) * NC + c] + v.w * Wc[(d0 + 3) * NC + c];
        p += __shfl_xor(p, 1, 64);
        p += __shfl_xor(p, 2, 64);
        p += __shfl_xor(p, 4, 64);
        p += __shfl_xor(p, 8, 64);
        logit[c] = p + bc[c];
    }
    float m = logit[0];
    #pragma unroll
    for (int c = 1; c < NC; ++c) m = fmaxf(m, logit[c]);
    float ssum = 0.f;
    #pragma unroll
    for (int c = 0; c < NC; ++c) ssum += __expf(logit[c] - m);
    out[base + ND + g] = __expf(logit[g] - m) / ssum;
}

extern "C" void kernel_launch(void* const* d_in, const int* in_sizes, int n_in,
                              void* d_out, int out_size, void* d_ws, size_t ws_size,
                              hipStream_t stream) {
    const float* x   = (const float*)d_in[0];
    const int* src   = (const int*)d_in[1];
    const int* dst   = (const int*)d_in[2];
    const float* W0  = (const float*)d_in[3];
    const float* al0 = (const float*)d_in[4];
    const float* ar0 = (const float*)d_in[5];
    const float* W1  = (const float*)d_in[6];
    const float* al1 = (const float*)d_in[7];
    const float* ar1 = (const float*)d_in[8];
    const float* Wc  = (const float*)d_in[9];
    const float* bc  = (const float*)d_in[10];
    float* out = (float*)d_out;

    char* ws = (char*)d_ws;
    size_t off = 0;
    auto alloc = [&](size_t bytes) { void* p = ws + off; off = (off + bytes + 255) & ~(size_t)255; return p; };
    ushort* featsl = (ushort*)alloc((size_t)N_NODES * NF * 2);   // 25.6 MB slice-major GEMM out
    ushort* xbf    = (ushort*)alloc((size_t)N_NODES * NF * 2);   // 25.6 MB
    ushort* hbuf   = (ushort*)alloc((size_t)N_NODES * NF * 2);   // 25.6 MB layer0 out (row-major)
    ushort* Wt0    = (ushort*)alloc((size_t)256 * 256 * 2);
    ushort* Wt1    = (ushort*)alloc((size_t)256 * 256 * 2);
    float*  el     = (float*)alloc((size_t)N_NODES * NH * 4);
    float*  er     = (float*)alloc((size_t)N_NODES * NH * 4);
    float*  wbuf   = (float*)alloc((size_t)N_EDGES * NH * 4);    // 12.8 MB head-major planes
    float*  denom  = (float*)alloc((size_t)N_NODES * NH * 4);    // 800 KB head-major planes
    int* counts    = (int*)alloc((size_t)N_NODES * 4);
    int* offs      = (int*)alloc((size_t)(N_NODES + 1) * 4);
    int* cursor    = (int*)alloc((size_t)N_NODES * 4);
    int* csrc      = (int*)alloc((size_t)N_EDGES * 4);
    int* cdst      = (int*)alloc((size_t)N_EDGES * 4);
    int* bsums     = (int*)alloc(256 * 4);
    int* boffs     = (int*)alloc(256 * 4);

    const int EB = (N_EDGES + 255) / 256;          // 3125
    const int NB = (N_NODES + 255) / 256;          // 196
    const int GEMM_MB = (N_NODES + 127) / 128;     // 391
    const int C8 = (N_NODES * NF / 8 + 255) / 256;
    const int AGG_B = NSLICE * ((N_NODES + 31) / 32);  // 8 * 1563 = 12504 blocks

    // ---- CSR build ----
    hipMemsetAsync(counts, 0, (size_t)N_NODES * 4, stream);
    hist_kernel<<<EB, 256, 0, stream>>>(dst, counts);
    scan1_kernel<<<NB, 256, 0, stream>>>(counts, offs, bsums);
    scan2_kernel<<<1, 256, 0, stream>>>(bsums, boffs, NB);
    scan3_kernel<<<NB, 256, 0, stream>>>(offs, boffs, cursor);
    scatter_kernel<<<EB, 256, 0, stream>>>(src, dst, cursor, csrc, cdst);

    // ---- weight + input casts ----
    castWt_kernel<<<512, 256, 0, stream>>>(W0, W1, Wt0, Wt1);
    cast_bf16_kernel<<<C8, 256, 0, stream>>>(x, xbf, N_NODES * NF / 8);

    // ---- Layer 0 ----
    gemm_bf16<<<dim3(GEMM_MB, 2), 256, 0, stream>>>(xbf, Wt0, featsl, al0, ar0, el, er, N_NODES);
    hipMemsetAsync(denom, 0, (size_t)N_NODES * NH * 4, stream);
    edge_w_kernel<<<EB, 256, 0, stream>>>(csrc, cdst, el, er, wbuf, denom);
    agg3_l0<<<AGG_B, 256, 0, stream>>>(featsl, csrc, offs, wbuf, denom, hbuf);

    // ---- Layer 1 ----
    gemm_bf16<<<dim3(GEMM_MB, 2), 256, 0, stream>>>(hbuf, Wt1, featsl, al1, ar1, el, er, N_NODES);
    hipMemsetAsync(denom, 0, (size_t)N_NODES * NH * 4, stream);
    edge_w_kernel<<<EB, 256, 0, stream>>>(csrc, cdst, el, er, wbuf, denom);
    agg3_final<<<AGG_B, 256, 0, stream>>>(featsl, csrc, offs, wbuf, denom, out);

    // ---- cluster softmax (needs full 64-wide heads) ----
    cluster_kernel<<<N_NODES / 4, 256, 0, stream>>>(Wc, bc, out);
}

// Round 11
// 423.729 us; speedup vs baseline: 2.7339x; 1.9275x over previous
//
#include <hip/hip_runtime.h>
#include <hip/hip_bf16.h>
#include <math.h>

#define N_NODES 50000
#define N_EDGES 800000
#define NH 4
#define ND 64
#define NF 256   // NH*ND = feature width everywhere (IN=256 too)
#define NC 16
#define NEG_SLOPE 0.2f
#define NSLICE 8      // feature slices (32 feats = 64B each), slice = blockIdx&7 -> XCD-pinned
#define SLICE_W 32

typedef __attribute__((ext_vector_type(8))) short bf16x8;
typedef __attribute__((ext_vector_type(4))) float f32x4;

__device__ __forceinline__ float elu_f(float x) {
    return x > 0.f ? x : (__expf(x) - 1.f);
}

__device__ __forceinline__ ushort bf16_rne(float f) {
    union { float f; unsigned u; } v; v.f = f;
    unsigned u = v.u;
    u += 0x7fffu + ((u >> 16) & 1u);   // round-to-nearest-even
    return (ushort)(u >> 16);
}

__device__ __forceinline__ float bf2f(ushort u) {
    return __uint_as_float(((unsigned)u) << 16);
}

// ---------------- cast x (f32) -> bf16 ----------------
__global__ __launch_bounds__(256) void cast_bf16_kernel(const float* __restrict__ in,
                                                        ushort* __restrict__ out, int n8) {
    int i = blockIdx.x * 256 + threadIdx.x;
    if (i >= n8) return;
    float4 a = *(const float4*)(in + i * 8);
    float4 b = *(const float4*)(in + i * 8 + 4);
    ushort o[8] = {bf16_rne(a.x), bf16_rne(a.y), bf16_rne(a.z), bf16_rne(a.w),
                   bf16_rne(b.x), bf16_rne(b.y), bf16_rne(b.z), bf16_rne(b.w)};
    *(bf16x8*)(out + i * 8) = *(bf16x8*)o;
}

// ---- transpose+cast W[k][n] f32 -> Wt[n][k] bf16, two weights in one launch ----
__global__ __launch_bounds__(256) void castWt_kernel(const float* __restrict__ W0,
                                                     const float* __restrict__ W1,
                                                     ushort* __restrict__ Wt0,
                                                     ushort* __restrict__ Wt1) {
    const float* W = (blockIdx.x < 256) ? W0 : W1;
    ushort* Wt = (blockIdx.x < 256) ? Wt0 : Wt1;
    int n = blockIdx.x & 255;
    int k = threadIdx.x;
    Wt[n * 256 + k] = bf16_rne(W[k * 256 + n]);
}

// ---------------- GEMM: Cs (slice-major bf16) = A[M,256]bf16 @ Bt[n][k]bf16 ----------------
// 128x128 tile, BK=64, 256 threads (4 waves 2x2), 16x16x32 MFMA, XOR-swizzled LDS.
// Epilogue: slice-major store Cs[(col>>5)][row][col&31] + fused el/er dots (HEAD-MAJOR planes).
__global__ __launch_bounds__(256) void gemm_bf16(const ushort* __restrict__ A,
                                                 const ushort* __restrict__ Bt,
                                                 ushort* __restrict__ Cs,
                                                 const float* __restrict__ al,
                                                 const float* __restrict__ ar,
                                                 float* __restrict__ el,
                                                 float* __restrict__ er, int M) {
    __shared__ __align__(16) ushort As[128 * 64];   // [row][k], 16B blocks XOR-swizzled
    __shared__ __align__(16) ushort Bs[128 * 64];   // [col][k], same
    const int t = threadIdx.x;
    const int l = t & 63;
    const int w = t >> 6;
    const int wm = (w >> 1) * 64, wn = (w & 1) * 64;
    const int m0 = blockIdx.x * 128, n0 = blockIdx.y * 128;
    const int lr = l & 15, lk = l >> 4;

    f32x4 acc[4][4] = {};
    const int sr = t >> 3;            // staging row-in-issue 0..31
    const int sc = t & 7;             // global 16B-block col
    const int scw = sc ^ (sr & 7);    // swizzled LDS block

    for (int k0 = 0; k0 < 256; k0 += 64) {
        #pragma unroll
        for (int q = 0; q < 4; ++q) {
            int row = q * 32 + sr;
            int ga = min(m0 + row, M - 1);
            bf16x8 va = *(const bf16x8*)(A + (size_t)ga * 256 + k0 + sc * 8);
            *(bf16x8*)(&As[row * 64 + scw * 8]) = va;
            bf16x8 vb = *(const bf16x8*)(Bt + (size_t)(n0 + row) * 256 + k0 + sc * 8);
            *(bf16x8*)(&Bs[row * 64 + scw * 8]) = vb;
        }
        __syncthreads();
        #pragma unroll
        for (int kk = 0; kk < 2; ++kk) {
            bf16x8 af[4], bfr[4];
            #pragma unroll
            for (int mi = 0; mi < 4; ++mi) {
                int row = wm + mi * 16 + lr;
                int kb = kk * 4 + lk;
                af[mi] = *(const bf16x8*)(&As[row * 64 + (kb ^ (row & 7)) * 8]);
            }
            #pragma unroll
            for (int ni = 0; ni < 4; ++ni) {
                int col = wn + ni * 16 + lr;
                int kb = kk * 4 + lk;
                bfr[ni] = *(const bf16x8*)(&Bs[col * 64 + (kb ^ (col & 7)) * 8]);
            }
            #pragma unroll
            for (int mi = 0; mi < 4; ++mi)
                #pragma unroll
                for (int ni = 0; ni < 4; ++ni)
                    acc[mi][ni] = __builtin_amdgcn_mfma_f32_16x16x32_bf16(af[mi], bfr[ni], acc[mi][ni], 0, 0, 0);
        }
        __syncthreads();
    }
    // this wave's head and its al/ar slice (d = ni*16 + lr)
    const int h = (n0 + wn) >> 6;
    float alv[4], arv[4];
    #pragma unroll
    for (int ni = 0; ni < 4; ++ni) {
        alv[ni] = al[h * ND + ni * 16 + lr];
        arv[ni] = ar[h * ND + ni * 16 + lr];
    }
    // C/D layout: col = lane&15, row = (lane>>4)*4 + reg  [m89-verified]
    #pragma unroll
    for (int mi = 0; mi < 4; ++mi) {
        #pragma unroll
        for (int j = 0; j < 4; ++j) {
            int row = m0 + wm + mi * 16 + lk * 4 + j;
            float pe = 0.f, pr = 0.f;
            #pragma unroll
            for (int ni = 0; ni < 4; ++ni) {
                int col = n0 + wn + ni * 16 + lr;
                float v = acc[mi][ni][j];
                pe += v * alv[ni];
                pr += v * arv[ni];
                if (row < M)
                    Cs[(size_t)(col >> 5) * N_NODES * SLICE_W + (size_t)row * SLICE_W + (col & 31)] = bf16_rne(v);
            }
            #pragma unroll
            for (int m = 1; m <= 8; m <<= 1) {
                pe += __shfl_xor(pe, m, 64);
                pr += __shfl_xor(pr, m, 64);
            }
            if (lr == 0 && row < M) {
                el[h * N_NODES + row] = pe;   // head-major planes
                er[h * N_NODES + row] = pr;
            }
        }
    }
}

// -------- CSR build --------
__global__ __launch_bounds__(256) void hist_kernel(const int* __restrict__ dst, int* __restrict__ count) {
    int e = blockIdx.x * 256 + threadIdx.x;
    if (e < N_EDGES) atomicAdd(&count[dst[e]], 1);
}

__global__ __launch_bounds__(256) void scan1_kernel(const int* __restrict__ counts,
                                                    int* __restrict__ offs,
                                                    int* __restrict__ bsums) {
    __shared__ int sh[256];
    int tid = threadIdx.x;
    int i = blockIdx.x * 256 + tid;
    int v = (i < N_NODES) ? counts[i] : 0;
    sh[tid] = v;
    __syncthreads();
    #pragma unroll
    for (int ofs = 1; ofs < 256; ofs <<= 1) {
        int t = (tid >= ofs) ? sh[tid - ofs] : 0;
        __syncthreads();
        sh[tid] += t;
        __syncthreads();
    }
    if (i < N_NODES) offs[i] = sh[tid] - v;
    if (tid == 255) bsums[blockIdx.x] = sh[255];
}

__global__ __launch_bounds__(256) void scan2_kernel(const int* __restrict__ bsums,
                                                    int* __restrict__ boffs, int nb) {
    __shared__ int sh[256];
    int tid = threadIdx.x;
    int v = (tid < nb) ? bsums[tid] : 0;
    sh[tid] = v;
    __syncthreads();
    #pragma unroll
    for (int ofs = 1; ofs < 256; ofs <<= 1) {
        int t = (tid >= ofs) ? sh[tid - ofs] : 0;
        __syncthreads();
        sh[tid] += t;
        __syncthreads();
    }
    if (tid < nb) boffs[tid] = sh[tid] - v;
}

// scan3: finalize offs AND init cursor
__global__ __launch_bounds__(256) void scan3_kernel(int* __restrict__ offs,
                                                    const int* __restrict__ boffs,
                                                    int* __restrict__ cursor) {
    int i = blockIdx.x * 256 + threadIdx.x;
    if (i < N_NODES) {
        int v = offs[i] + boffs[i >> 8];
        offs[i] = v;
        cursor[i] = v;
    }
    if (i == 0) offs[N_NODES] = N_EDGES;
}

// scatter: store src node id per slot
__global__ __launch_bounds__(256) void scatter_kernel(const int* __restrict__ src,
                                                      const int* __restrict__ dst,
                                                      int* __restrict__ cursor,
                                                      int* __restrict__ csrc) {
    int e = blockIdx.x * 256 + threadIdx.x;
    if (e >= N_EDGES) return;
    int p = atomicAdd(&cursor[dst[e]], 1);
    csrc[p] = src[e];
}

// ======== sliced aggregation v4: wave = 8 nodes x 1 slice, fully fused, no atomics ========
// lane = (nn 0..7, fc 0..7): 8-lane group owns node nn's 64B slice row.
// Weight wv = exp(leaky(el[h][sid]+er[h][n])) computed inline; it is UNIFORM across the
// 8-lane group, so dsum += wv per lane IS the exact softmax denom — no reduce, no atomics.
// 4-deep NAMED unroll (no arrays -> no scratch): 12 independent loads in flight per group.
// slice = blockIdx&7 -> XCD-pinned 3.2MB working set [r8-proven].
#define AGG4_BODY()                                                                 \
    int b = blockIdx.x;                                                             \
    int slice = b & 7;                                                              \
    int wid = threadIdx.x >> 6;                                                     \
    int lane = threadIdx.x & 63;                                                    \
    int nn = lane >> 3;                                                             \
    int fc = lane & 7;                                                              \
    int h = slice >> 1;                                                             \
    int n = (b >> 3) * 32 + wid * 8 + nn;                                           \
    int nc = min(n, N_NODES - 1);                                                   \
    const ushort* base = fs + (size_t)slice * (N_NODES * SLICE_W);                  \
    const float* elh = el + (size_t)h * N_NODES;                                    \
    int s0 = offs[nc];                                                              \
    int deg = (n < N_NODES) ? (offs[nc + 1] - s0) : 0;                              \
    int degc = max(deg - 1, 0);                                                     \
    float ern = er[(size_t)h * N_NODES + nc];                                       \
    int md = deg;                                                                   \
    md = max(md, __shfl_xor(md, 8, 64));                                            \
    md = max(md, __shfl_xor(md, 16, 64));                                           \
    md = max(md, __shfl_xor(md, 32, 64));                                           \
    float4 acc = make_float4(0.f, 0.f, 0.f, 0.f);                                   \
    float dsum = 0.f;                                                               \
    for (int t = 0; t < md; t += 4) {                                               \
        int i0 = s0 + min(t + 0, degc);                                             \
        int i1 = s0 + min(t + 1, degc);                                             \
        int i2 = s0 + min(t + 2, degc);                                             \
        int i3 = s0 + min(t + 3, degc);                                             \
        int a0 = csrc[i0];                                                          \
        int a1 = csrc[i1];                                                          \
        int a2 = csrc[i2];                                                          \
        int a3 = csrc[i3];                                                          \
        float e0 = elh[a0];                                                         \
        float e1 = elh[a1];                                                         \
        float e2 = elh[a2];                                                         \
        float e3 = elh[a3];                                                         \
        ushort4 q0 = *(const ushort4*)(base + a0 * SLICE_W + fc * 4);               \
        ushort4 q1 = *(const ushort4*)(base + a1 * SLICE_W + fc * 4);               \
        ushort4 q2 = *(const ushort4*)(base + a2 * SLICE_W + fc * 4);               \
        ushort4 q3 = *(const ushort4*)(base + a3 * SLICE_W + fc * 4);               \
        float x0 = e0 + ern; x0 = fmaxf(x0, NEG_SLOPE * x0);                        \
        float x1 = e1 + ern; x1 = fmaxf(x1, NEG_SLOPE * x1);                        \
        float x2 = e2 + ern; x2 = fmaxf(x2, NEG_SLOPE * x2);                        \
        float x3 = e3 + ern; x3 = fmaxf(x3, NEG_SLOPE * x3);                        \
        float w0 = (t + 0 < deg) ? __expf(x0) : 0.f;                                \
        float w1 = (t + 1 < deg) ? __expf(x1) : 0.f;                                \
        float w2 = (t + 2 < deg) ? __expf(x2) : 0.f;                                \
        float w3 = (t + 3 < deg) ? __expf(x3) : 0.f;                                \
        acc.x += w0 * bf2f(q0.x) + w1 * bf2f(q1.x) + w2 * bf2f(q2.x) + w3 * bf2f(q3.x); \
        acc.y += w0 * bf2f(q0.y) + w1 * bf2f(q1.y) + w2 * bf2f(q2.y) + w3 * bf2f(q3.y); \
        acc.z += w0 * bf2f(q0.z) + w1 * bf2f(q1.z) + w2 * bf2f(q2.z) + w3 * bf2f(q3.z); \
        acc.w += w0 * bf2f(q0.w) + w1 * bf2f(q1.w) + w2 * bf2f(q2.w) + w3 * bf2f(q3.w); \
        dsum += w0 + w1 + w2 + w3;                                                  \
    }                                                                               \
    float inv = 1.f / fmaxf(dsum, 1e-9f);

// layer-0: write bf16 row-major hbuf (GEMM-1 A input)
__global__ __launch_bounds__(256) void agg4_l0(const ushort* __restrict__ fs,
                                               const int* __restrict__ csrc,
                                               const int* __restrict__ offs,
                                               const float* __restrict__ el,
                                               const float* __restrict__ er,
                                               ushort* __restrict__ hbuf) {
    AGG4_BODY()
    if (n < N_NODES) {
        ushort o[4] = {bf16_rne(elu_f(acc.x * inv)), bf16_rne(elu_f(acc.y * inv)),
                       bf16_rne(elu_f(acc.z * inv)), bf16_rne(elu_f(acc.w * inv))};
        *(ushort4*)(hbuf + (size_t)n * NF + slice * SLICE_W + fc * 4) = *(ushort4*)o;
    }
}

// final layer: write f32 heads into out[h][n][(slice&1)*32 + fc*4 ..]
__global__ __launch_bounds__(256) void agg4_final(const ushort* __restrict__ fs,
                                                  const int* __restrict__ csrc,
                                                  const int* __restrict__ offs,
                                                  const float* __restrict__ el,
                                                  const float* __restrict__ er,
                                                  float* __restrict__ out) {
    AGG4_BODY()
    if (n < N_NODES) {
        float4 v = make_float4(elu_f(acc.x * inv), elu_f(acc.y * inv),
                               elu_f(acc.z * inv), elu_f(acc.w * inv));
        size_t p = (size_t)h * N_NODES * (ND + NC) + (size_t)n * (ND + NC)
                 + (slice & 1) * SLICE_W + fc * 4;
        *(float4*)(out + p) = v;
    }
}

// -------- cluster softmax pass: reads heads from out, writes cs --------
__global__ __launch_bounds__(256) void cluster_kernel(const float* __restrict__ Wc,
                                                      const float* __restrict__ bc,
                                                      float* __restrict__ out) {
    int n = blockIdx.x * 4 + (threadIdx.x >> 6);
    int lane = threadIdx.x & 63;
    int h = lane >> 4;
    int g = lane & 15;
    size_t base = (size_t)h * N_NODES * (ND + NC) + (size_t)n * (ND + NC);
    float4 v = *(const float4*)(out + base + g * 4);
    float logit[NC];
    #pragma unroll
    for (int c = 0; c < NC; ++c) {
        int d0 = g * 4;
        float p = v.x * Wc[(d0 + 0) * NC + c] + v.y * Wc[(d0 + 1) * NC + c] +
                  v.z * Wc[(d0 + 2) * NC + c] + v.w * Wc[(d0 + 3) * NC + c];
        p += __shfl_xor(p, 1, 64);
        p += __shfl_xor(p, 2, 64);
        p += __shfl_xor(p, 4, 64);
        p += __shfl_xor(p, 8, 64);
        logit[c] = p + bc[c];
    }
    float m = logit[0];
    #pragma unroll
    for (int c = 1; c < NC; ++c) m = fmaxf(m, logit[c]);
    float ssum = 0.f;
    #pragma unroll
    for (int c = 0; c < NC; ++c) ssum += __expf(logit[c] - m);
    out[base + ND + g] = __expf(logit[g] - m) / ssum;
}

extern "C" void kernel_launch(void* const* d_in, const int* in_sizes, int n_in,
                              void* d_out, int out_size, void* d_ws, size_t ws_size,
                              hipStream_t stream) {
    const float* x   = (const float*)d_in[0];
    const int* src   = (const int*)d_in[1];
    const int* dst   = (const int*)d_in[2];
    const float* W0  = (const float*)d_in[3];
    const float* al0 = (const float*)d_in[4];
    const float* ar0 = (const float*)d_in[5];
    const float* W1  = (const float*)d_in[6];
    const float* al1 = (const float*)d_in[7];
    const float* ar1 = (const float*)d_in[8];
    const float* Wc  = (const float*)d_in[9];
    const float* bc  = (const float*)d_in[10];
    float* out = (float*)d_out;

    char* ws = (char*)d_ws;
    size_t off = 0;
    auto alloc = [&](size_t bytes) { void* p = ws + off; off = (off + bytes + 255) & ~(size_t)255; return p; };
    ushort* featsl = (ushort*)alloc((size_t)N_NODES * NF * 2);   // 25.6 MB slice-major GEMM out
    ushort* xbf    = (ushort*)alloc((size_t)N_NODES * NF * 2);   // 25.6 MB
    ushort* hbuf   = (ushort*)alloc((size_t)N_NODES * NF * 2);   // 25.6 MB layer0 out (row-major)
    ushort* Wt0    = (ushort*)alloc((size_t)256 * 256 * 2);
    ushort* Wt1    = (ushort*)alloc((size_t)256 * 256 * 2);
    float*  el     = (float*)alloc((size_t)N_NODES * NH * 4);    // head-major planes
    float*  er     = (float*)alloc((size_t)N_NODES * NH * 4);    // head-major planes
    int* counts    = (int*)alloc((size_t)N_NODES * 4);
    int* offs      = (int*)alloc((size_t)(N_NODES + 1) * 4);
    int* cursor    = (int*)alloc((size_t)N_NODES * 4);
    int* csrc      = (int*)alloc((size_t)N_EDGES * 4);
    int* bsums     = (int*)alloc(256 * 4);
    int* boffs     = (int*)alloc(256 * 4);

    const int EB = (N_EDGES + 255) / 256;          // 3125
    const int NB = (N_NODES + 255) / 256;          // 196
    const int GEMM_MB = (N_NODES + 127) / 128;     // 391
    const int C8 = (N_NODES * NF / 8 + 255) / 256;
    const int AGG_B = NSLICE * ((N_NODES + 31) / 32);  // 8 * 1563 = 12504 blocks

    // ---- CSR build ----
    hipMemsetAsync(counts, 0, (size_t)N_NODES * 4, stream);
    hist_kernel<<<EB, 256, 0, stream>>>(dst, counts);
    scan1_kernel<<<NB, 256, 0, stream>>>(counts, offs, bsums);
    scan2_kernel<<<1, 256, 0, stream>>>(bsums, boffs, NB);
    scan3_kernel<<<NB, 256, 0, stream>>>(offs, boffs, cursor);
    scatter_kernel<<<EB, 256, 0, stream>>>(src, dst, cursor, csrc);

    // ---- weight + input casts ----
    castWt_kernel<<<512, 256, 0, stream>>>(W0, W1, Wt0, Wt1);
    cast_bf16_kernel<<<C8, 256, 0, stream>>>(x, xbf, N_NODES * NF / 8);

    // ---- Layer 0 ----
    gemm_bf16<<<dim3(GEMM_MB, 2), 256, 0, stream>>>(xbf, Wt0, featsl, al0, ar0, el, er, N_NODES);
    agg4_l0<<<AGG_B, 256, 0, stream>>>(featsl, csrc, offs, el, er, hbuf);

    // ---- Layer 1 ----
    gemm_bf16<<<dim3(GEMM_MB, 2), 256, 0, stream>>>(hbuf, Wt1, featsl, al1, ar1, el, er, N_NODES);
    agg4_final<<<AGG_B, 256, 0, stream>>>(featsl, csrc, offs, el, er, out);

    // ---- cluster softmax (needs full 64-wide heads) ----
    cluster_kernel<<<N_NODES / 4, 256, 0, stream>>>(Wc, bc, out);
}

// Round 12
// 363.640 us; speedup vs baseline: 3.1857x; 1.1652x over previous
//
#include <hip/hip_runtime.h>
#include <hip/hip_bf16.h>
#include <math.h>

#define N_NODES 50000
#define N_EDGES 800000
#define NH 4
#define ND 64
#define NF 256   // NH*ND = feature width everywhere (IN=256 too)
#define NC 16
#define NEG_SLOPE 0.2f
#define NSLICE 8      // feature slices (32 feats = 64B each), slice = blockIdx&7 -> XCD-pinned
#define SLICE_W 32

typedef __attribute__((ext_vector_type(8))) short bf16x8;
typedef __attribute__((ext_vector_type(4))) float f32x4;

__device__ __forceinline__ float elu_f(float x) {
    return x > 0.f ? x : (__expf(x) - 1.f);
}

__device__ __forceinline__ ushort bf16_rne(float f) {
    union { float f; unsigned u; } v; v.f = f;
    unsigned u = v.u;
    u += 0x7fffu + ((u >> 16) & 1u);   // round-to-nearest-even
    return (ushort)(u >> 16);
}

__device__ __forceinline__ float bf2f(ushort u) {
    return __uint_as_float(((unsigned)u) << 16);
}

// ---------------- cast x (f32) -> bf16 ----------------
__global__ __launch_bounds__(256) void cast_bf16_kernel(const float* __restrict__ in,
                                                        ushort* __restrict__ out, int n8) {
    int i = blockIdx.x * 256 + threadIdx.x;
    if (i >= n8) return;
    float4 a = *(const float4*)(in + i * 8);
    float4 b = *(const float4*)(in + i * 8 + 4);
    ushort o[8] = {bf16_rne(a.x), bf16_rne(a.y), bf16_rne(a.z), bf16_rne(a.w),
                   bf16_rne(b.x), bf16_rne(b.y), bf16_rne(b.z), bf16_rne(b.w)};
    *(bf16x8*)(out + i * 8) = *(bf16x8*)o;
}

// ---- transpose+cast W[k][n] f32 -> Wt[n][k] bf16, two weights in one launch ----
__global__ __launch_bounds__(256) void castWt_kernel(const float* __restrict__ W0,
                                                     const float* __restrict__ W1,
                                                     ushort* __restrict__ Wt0,
                                                     ushort* __restrict__ Wt1) {
    const float* W = (blockIdx.x < 256) ? W0 : W1;
    ushort* Wt = (blockIdx.x < 256) ? Wt0 : Wt1;
    int n = blockIdx.x & 255;
    int k = threadIdx.x;
    Wt[n * 256 + k] = bf16_rne(W[k * 256 + n]);
}

// ---------------- GEMM: Cs (slice-major bf16) = A[M,256]bf16 @ Bt[n][k]bf16 ----------------
// 128x128 tile, BK=64, 256 threads (4 waves 2x2), 16x16x32 MFMA, XOR-swizzled LDS.
// Epilogue: slice-major store Cs[(col>>5)][row][col&31] + fused el/er dots (HEAD-MAJOR planes).
__global__ __launch_bounds__(256) void gemm_bf16(const ushort* __restrict__ A,
                                                 const ushort* __restrict__ Bt,
                                                 ushort* __restrict__ Cs,
                                                 const float* __restrict__ al,
                                                 const float* __restrict__ ar,
                                                 float* __restrict__ el,
                                                 float* __restrict__ er, int M) {
    __shared__ __align__(16) ushort As[128 * 64];   // [row][k], 16B blocks XOR-swizzled
    __shared__ __align__(16) ushort Bs[128 * 64];   // [col][k], same
    const int t = threadIdx.x;
    const int l = t & 63;
    const int w = t >> 6;
    const int wm = (w >> 1) * 64, wn = (w & 1) * 64;
    const int m0 = blockIdx.x * 128, n0 = blockIdx.y * 128;
    const int lr = l & 15, lk = l >> 4;

    f32x4 acc[4][4] = {};
    const int sr = t >> 3;            // staging row-in-issue 0..31
    const int sc = t & 7;             // global 16B-block col
    const int scw = sc ^ (sr & 7);    // swizzled LDS block

    for (int k0 = 0; k0 < 256; k0 += 64) {
        #pragma unroll
        for (int q = 0; q < 4; ++q) {
            int row = q * 32 + sr;
            int ga = min(m0 + row, M - 1);
            bf16x8 va = *(const bf16x8*)(A + (size_t)ga * 256 + k0 + sc * 8);
            *(bf16x8*)(&As[row * 64 + scw * 8]) = va;
            bf16x8 vb = *(const bf16x8*)(Bt + (size_t)(n0 + row) * 256 + k0 + sc * 8);
            *(bf16x8*)(&Bs[row * 64 + scw * 8]) = vb;
        }
        __syncthreads();
        #pragma unroll
        for (int kk = 0; kk < 2; ++kk) {
            bf16x8 af[4], bfr[4];
            #pragma unroll
            for (int mi = 0; mi < 4; ++mi) {
                int row = wm + mi * 16 + lr;
                int kb = kk * 4 + lk;
                af[mi] = *(const bf16x8*)(&As[row * 64 + (kb ^ (row & 7)) * 8]);
            }
            #pragma unroll
            for (int ni = 0; ni < 4; ++ni) {
                int col = wn + ni * 16 + lr;
                int kb = kk * 4 + lk;
                bfr[ni] = *(const bf16x8*)(&Bs[col * 64 + (kb ^ (col & 7)) * 8]);
            }
            #pragma unroll
            for (int mi = 0; mi < 4; ++mi)
                #pragma unroll
                for (int ni = 0; ni < 4; ++ni)
                    acc[mi][ni] = __builtin_amdgcn_mfma_f32_16x16x32_bf16(af[mi], bfr[ni], acc[mi][ni], 0, 0, 0);
        }
        __syncthreads();
    }
    // this wave's head and its al/ar slice (d = ni*16 + lr)
    const int h = (n0 + wn) >> 6;
    float alv[4], arv[4];
    #pragma unroll
    for (int ni = 0; ni < 4; ++ni) {
        alv[ni] = al[h * ND + ni * 16 + lr];
        arv[ni] = ar[h * ND + ni * 16 + lr];
    }
    // C/D layout: col = lane&15, row = (lane>>4)*4 + reg  [m89-verified]
    #pragma unroll
    for (int mi = 0; mi < 4; ++mi) {
        #pragma unroll
        for (int j = 0; j < 4; ++j) {
            int row = m0 + wm + mi * 16 + lk * 4 + j;
            float pe = 0.f, pr = 0.f;
            #pragma unroll
            for (int ni = 0; ni < 4; ++ni) {
                int col = n0 + wn + ni * 16 + lr;
                float v = acc[mi][ni][j];
                pe += v * alv[ni];
                pr += v * arv[ni];
                if (row < M)
                    Cs[(size_t)(col >> 5) * N_NODES * SLICE_W + (size_t)row * SLICE_W + (col & 31)] = bf16_rne(v);
            }
            #pragma unroll
            for (int m = 1; m <= 8; m <<= 1) {
                pe += __shfl_xor(pe, m, 64);
                pr += __shfl_xor(pr, m, 64);
            }
            if (lr == 0 && row < M) {
                el[h * N_NODES + row] = pe;   // head-major planes
                er[h * N_NODES + row] = pr;
            }
        }
    }
}

// -------- CSR build --------
__global__ __launch_bounds__(256) void hist_kernel(const int* __restrict__ dst, int* __restrict__ count) {
    int e = blockIdx.x * 256 + threadIdx.x;
    if (e < N_EDGES) atomicAdd(&count[dst[e]], 1);
}

__global__ __launch_bounds__(256) void scan1_kernel(const int* __restrict__ counts,
                                                    int* __restrict__ offs,
                                                    int* __restrict__ bsums) {
    __shared__ int sh[256];
    int tid = threadIdx.x;
    int i = blockIdx.x * 256 + tid;
    int v = (i < N_NODES) ? counts[i] : 0;
    sh[tid] = v;
    __syncthreads();
    #pragma unroll
    for (int ofs = 1; ofs < 256; ofs <<= 1) {
        int t = (tid >= ofs) ? sh[tid - ofs] : 0;
        __syncthreads();
        sh[tid] += t;
        __syncthreads();
    }
    if (i < N_NODES) offs[i] = sh[tid] - v;
    if (tid == 255) bsums[blockIdx.x] = sh[255];
}

__global__ __launch_bounds__(256) void scan2_kernel(const int* __restrict__ bsums,
                                                    int* __restrict__ boffs, int nb) {
    __shared__ int sh[256];
    int tid = threadIdx.x;
    int v = (tid < nb) ? bsums[tid] : 0;
    sh[tid] = v;
    __syncthreads();
    #pragma unroll
    for (int ofs = 1; ofs < 256; ofs <<= 1) {
        int t = (tid >= ofs) ? sh[tid - ofs] : 0;
        __syncthreads();
        sh[tid] += t;
        __syncthreads();
    }
    if (tid < nb) boffs[tid] = sh[tid] - v;
}

// scan3: finalize offs AND init cursor
__global__ __launch_bounds__(256) void scan3_kernel(int* __restrict__ offs,
                                                    const int* __restrict__ boffs,
                                                    int* __restrict__ cursor) {
    int i = blockIdx.x * 256 + threadIdx.x;
    if (i < N_NODES) {
        int v = offs[i] + boffs[i >> 8];
        offs[i] = v;
        cursor[i] = v;
    }
    if (i == 0) offs[N_NODES] = N_EDGES;
}

// scatter: store src node id per slot
__global__ __launch_bounds__(256) void scatter_kernel(const int* __restrict__ src,
                                                      const int* __restrict__ dst,
                                                      int* __restrict__ cursor,
                                                      int* __restrict__ csrc) {
    int e = blockIdx.x * 256 + threadIdx.x;
    if (e >= N_EDGES) return;
    int p = atomicAdd(&cursor[dst[e]], 1);
    csrc[p] = src[e];
}

// ======== sliced aggregation v5: wave = 8 nodes x 1 slice, 8-deep named unroll ========
// lane = (nn 0..7, fc 0..7): 8-lane group owns node nn's 64B slice row.
// Weight wv computed inline; uniform across the 8-lane group, so dsum += wv per lane
// IS the exact softmax denom — no reduce, no atomics.
// 8-deep NAMED unroll (no arrays -> no scratch): 24 independent loads/group in flight.
// slice = blockIdx&7 -> XCD-pinned 3.2MB working set [r8-proven].
#define AGG5_EDGE(K)                                                                \
        int i##K = s0 + min(t + K, degc);                                           \
        int a##K = csrc[i##K];
#define AGG5_EL(K)                                                                  \
        float e##K = elh[a##K];
#define AGG5_Q(K)                                                                   \
        ushort4 q##K = *(const ushort4*)(base + a##K * SLICE_W + fc * 4);
#define AGG5_W(K)                                                                   \
        float x##K = e##K + ern; x##K = fmaxf(x##K, NEG_SLOPE * x##K);              \
        float w##K = (t + K < deg) ? __expf(x##K) : 0.f;
#define AGG5_ACC(K)                                                                 \
        acc.x += w##K * bf2f(q##K.x);                                               \
        acc.y += w##K * bf2f(q##K.y);                                               \
        acc.z += w##K * bf2f(q##K.z);                                               \
        acc.w += w##K * bf2f(q##K.w);                                               \
        dsum += w##K;

#define AGG5_BODY()                                                                 \
    int b = blockIdx.x;                                                             \
    int slice = b & 7;                                                              \
    int wid = threadIdx.x >> 6;                                                     \
    int lane = threadIdx.x & 63;                                                    \
    int nn = lane >> 3;                                                             \
    int fc = lane & 7;                                                              \
    int h = slice >> 1;                                                             \
    int n = (b >> 3) * 32 + wid * 8 + nn;                                           \
    int nc = min(n, N_NODES - 1);                                                   \
    const ushort* base = fs + (size_t)slice * (N_NODES * SLICE_W);                  \
    const float* elh = el + (size_t)h * N_NODES;                                    \
    int s0 = offs[nc];                                                              \
    int deg = (n < N_NODES) ? (offs[nc + 1] - s0) : 0;                              \
    int degc = max(deg - 1, 0);                                                     \
    float ern = er[(size_t)h * N_NODES + nc];                                       \
    int md = deg;                                                                   \
    md = max(md, __shfl_xor(md, 8, 64));                                            \
    md = max(md, __shfl_xor(md, 16, 64));                                           \
    md = max(md, __shfl_xor(md, 32, 64));                                           \
    float4 acc = make_float4(0.f, 0.f, 0.f, 0.f);                                   \
    float dsum = 0.f;                                                               \
    for (int t = 0; t < md; t += 8) {                                               \
        AGG5_EDGE(0) AGG5_EDGE(1) AGG5_EDGE(2) AGG5_EDGE(3)                         \
        AGG5_EDGE(4) AGG5_EDGE(5) AGG5_EDGE(6) AGG5_EDGE(7)                         \
        AGG5_EL(0) AGG5_EL(1) AGG5_EL(2) AGG5_EL(3)                                 \
        AGG5_EL(4) AGG5_EL(5) AGG5_EL(6) AGG5_EL(7)                                 \
        AGG5_Q(0) AGG5_Q(1) AGG5_Q(2) AGG5_Q(3)                                     \
        AGG5_Q(4) AGG5_Q(5) AGG5_Q(6) AGG5_Q(7)                                     \
        AGG5_W(0) AGG5_W(1) AGG5_W(2) AGG5_W(3)                                     \
        AGG5_W(4) AGG5_W(5) AGG5_W(6) AGG5_W(7)                                     \
        AGG5_ACC(0) AGG5_ACC(1) AGG5_ACC(2) AGG5_ACC(3)                             \
        AGG5_ACC(4) AGG5_ACC(5) AGG5_ACC(6) AGG5_ACC(7)                             \
    }                                                                               \
    float inv = 1.f / fmaxf(dsum, 1e-9f);

// layer-0: write bf16 row-major hbuf (GEMM-1 A input)
__global__ __launch_bounds__(256) void agg5_l0(const ushort* __restrict__ fs,
                                               const int* __restrict__ csrc,
                                               const int* __restrict__ offs,
                                               const float* __restrict__ el,
                                               const float* __restrict__ er,
                                               ushort* __restrict__ hbuf) {
    AGG5_BODY()
    if (n < N_NODES) {
        ushort o[4] = {bf16_rne(elu_f(acc.x * inv)), bf16_rne(elu_f(acc.y * inv)),
                       bf16_rne(elu_f(acc.z * inv)), bf16_rne(elu_f(acc.w * inv))};
        *(ushort4*)(hbuf + (size_t)n * NF + slice * SLICE_W + fc * 4) = *(ushort4*)o;
    }
}

// final layer: write f32 heads into out[h][n][(slice&1)*32 + fc*4 ..]
__global__ __launch_bounds__(256) void agg5_final(const ushort* __restrict__ fs,
                                                  const int* __restrict__ csrc,
                                                  const int* __restrict__ offs,
                                                  const float* __restrict__ el,
                                                  const float* __restrict__ er,
                                                  float* __restrict__ out) {
    AGG5_BODY()
    if (n < N_NODES) {
        float4 v = make_float4(elu_f(acc.x * inv), elu_f(acc.y * inv),
                               elu_f(acc.z * inv), elu_f(acc.w * inv));
        size_t p = (size_t)h * N_NODES * (ND + NC) + (size_t)n * (ND + NC)
                 + (slice & 1) * SLICE_W + fc * 4;
        *(float4*)(out + p) = v;
    }
}

// -------- cluster softmax v2: one logit per lane (h,c), Wc in LDS --------
// wave = 1 node; lane = (h 0..3, c 0..15). Head values read as group-broadcast float4;
// softmax = 8 shfls total. Zero redundant logit computation.
__global__ __launch_bounds__(256) void cluster_kernel(const float* __restrict__ Wc,
                                                      const float* __restrict__ bc,
                                                      float* __restrict__ out) {
    __shared__ float WcS[ND * NC];   // 4 KB, [d][c]
    __shared__ float bcS[NC];
    int tid = threadIdx.x;
    #pragma unroll
    for (int i = 0; i < 4; ++i) WcS[i * 256 + tid] = Wc[i * 256 + tid];
    if (tid < NC) bcS[tid] = bc[tid];
    __syncthreads();
    int wid = tid >> 6;
    int lane = tid & 63;
    int h = lane >> 4, c = lane & 15;
    int n = blockIdx.x * 4 + wid;
    size_t base = (size_t)h * N_NODES * (ND + NC) + (size_t)n * (ND + NC);
    const float* hp = out + base;
    float acc = bcS[c];
    #pragma unroll
    for (int dd = 0; dd < 16; ++dd) {
        float4 f4 = *(const float4*)(hp + dd * 4);      // same addr across 16-lane group
        acc += f4.x * WcS[(dd * 4 + 0) * NC + c];
        acc += f4.y * WcS[(dd * 4 + 1) * NC + c];
        acc += f4.z * WcS[(dd * 4 + 2) * NC + c];
        acc += f4.w * WcS[(dd * 4 + 3) * NC + c];
    }
    float m = acc;
    m = fmaxf(m, __shfl_xor(m, 1, 64));
    m = fmaxf(m, __shfl_xor(m, 2, 64));
    m = fmaxf(m, __shfl_xor(m, 4, 64));
    m = fmaxf(m, __shfl_xor(m, 8, 64));
    float e = __expf(acc - m);
    float s = e;
    s += __shfl_xor(s, 1, 64);
    s += __shfl_xor(s, 2, 64);
    s += __shfl_xor(s, 4, 64);
    s += __shfl_xor(s, 8, 64);
    out[base + ND + c] = e / s;
}

extern "C" void kernel_launch(void* const* d_in, const int* in_sizes, int n_in,
                              void* d_out, int out_size, void* d_ws, size_t ws_size,
                              hipStream_t stream) {
    const float* x   = (const float*)d_in[0];
    const int* src   = (const int*)d_in[1];
    const int* dst   = (const int*)d_in[2];
    const float* W0  = (const float*)d_in[3];
    const float* al0 = (const float*)d_in[4];
    const float* ar0 = (const float*)d_in[5];
    const float* W1  = (const float*)d_in[6];
    const float* al1 = (const float*)d_in[7];
    const float* ar1 = (const float*)d_in[8];
    const float* Wc  = (const float*)d_in[9];
    const float* bc  = (const float*)d_in[10];
    float* out = (float*)d_out;

    char* ws = (char*)d_ws;
    size_t off = 0;
    auto alloc = [&](size_t bytes) { void* p = ws + off; off = (off + bytes + 255) & ~(size_t)255; return p; };
    ushort* featsl = (ushort*)alloc((size_t)N_NODES * NF * 2);   // 25.6 MB slice-major GEMM out
    ushort* xbf    = (ushort*)alloc((size_t)N_NODES * NF * 2);   // 25.6 MB
    ushort* hbuf   = (ushort*)alloc((size_t)N_NODES * NF * 2);   // 25.6 MB layer0 out (row-major)
    ushort* Wt0    = (ushort*)alloc((size_t)256 * 256 * 2);
    ushort* Wt1    = (ushort*)alloc((size_t)256 * 256 * 2);
    float*  el     = (float*)alloc((size_t)N_NODES * NH * 4);    // head-major planes
    float*  er     = (float*)alloc((size_t)N_NODES * NH * 4);    // head-major planes
    int* counts    = (int*)alloc((size_t)N_NODES * 4);
    int* offs      = (int*)alloc((size_t)(N_NODES + 1) * 4);
    int* cursor    = (int*)alloc((size_t)N_NODES * 4);
    int* csrc      = (int*)alloc((size_t)N_EDGES * 4);
    int* bsums     = (int*)alloc(256 * 4);
    int* boffs     = (int*)alloc(256 * 4);

    const int EB = (N_EDGES + 255) / 256;          // 3125
    const int NB = (N_NODES + 255) / 256;          // 196
    const int GEMM_MB = (N_NODES + 127) / 128;     // 391
    const int C8 = (N_NODES * NF / 8 + 255) / 256;
    const int AGG_B = NSLICE * ((N_NODES + 31) / 32);  // 8 * 1563 = 12504 blocks

    // ---- CSR build ----
    hipMemsetAsync(counts, 0, (size_t)N_NODES * 4, stream);
    hist_kernel<<<EB, 256, 0, stream>>>(dst, counts);
    scan1_kernel<<<NB, 256, 0, stream>>>(counts, offs, bsums);
    scan2_kernel<<<1, 256, 0, stream>>>(bsums, boffs, NB);
    scan3_kernel<<<NB, 256, 0, stream>>>(offs, boffs, cursor);
    scatter_kernel<<<EB, 256, 0, stream>>>(src, dst, cursor, csrc);

    // ---- weight + input casts ----
    castWt_kernel<<<512, 256, 0, stream>>>(W0, W1, Wt0, Wt1);
    cast_bf16_kernel<<<C8, 256, 0, stream>>>(x, xbf, N_NODES * NF / 8);

    // ---- Layer 0 ----
    gemm_bf16<<<dim3(GEMM_MB, 2), 256, 0, stream>>>(xbf, Wt0, featsl, al0, ar0, el, er, N_NODES);
    agg5_l0<<<AGG_B, 256, 0, stream>>>(featsl, csrc, offs, el, er, hbuf);

    // ---- Layer 1 ----
    gemm_bf16<<<dim3(GEMM_MB, 2), 256, 0, stream>>>(hbuf, Wt1, featsl, al1, ar1, el, er, N_NODES);
    agg5_final<<<AGG_B, 256, 0, stream>>>(featsl, csrc, offs, el, er, out);

    // ---- cluster softmax ----
    cluster_kernel<<<N_NODES / 4, 256, 0, stream>>>(Wc, bc, out);
}